// Round 4
// baseline (252.055 us; speedup 1.0000x reference)
//
#include <hip/hip_runtime.h>
#include <hip/hip_bf16.h>

#define HW1K  1048576    // 1024*1024

typedef float f4 __attribute__((ext_vector_type(4)));
typedef float f2 __attribute__((ext_vector_type(2)));

// Weight-prep: OIHW -> wp[layer_base + (ci*9+ky*3+kx)*COUT + co] (co fastest:
// coalesced + float4-loadable over co).
// Bases: L1@0(432) L2@432(4608) L3@5040(9216) L4@14256(18432) L5@32688(36864)
// L6@69552(55296), total 124848.
__global__ void prep_w(const float* __restrict__ w1, const float* __restrict__ w2,
                       const float* __restrict__ w3, const float* __restrict__ w4,
                       const float* __restrict__ w5, const float* __restrict__ w6,
                       float* __restrict__ wp) {
    int i = blockIdx.x * 256 + threadIdx.x;
    if (i >= 124848) return;
    const float* src; int base, cin, cout;
    if      (i < 432)   { src = w1; base = 0;     cin = 3;  cout = 16; }
    else if (i < 5040)  { src = w2; base = 432;   cin = 16; cout = 32; }
    else if (i < 14256) { src = w3; base = 5040;  cin = 32; cout = 32; }
    else if (i < 32688) { src = w4; base = 14256; cin = 32; cout = 64; }
    else if (i < 69552) { src = w5; base = 32688; cin = 64; cout = 64; }
    else                { src = w6; base = 69552; cin = 64; cout = 96; }
    int r  = i - base;
    int kk = r / cout;
    int co = r % cout;
    int ci = kk / 9;
    int t9 = kk % 9;
    wp[i] = src[(co * cin + ci) * 9 + t9];
}

// ---------------------------------------------------------------------------
// One VALID 3x3 conv layer on LDS tiles (512 threads).
// sIn stride SI=CIN+1, sOut stride SO=COUT+1 (bank-conflict pad; weights in
// global stay float4-aligned). Thread = (cog = tid%COG, pixel-slot ps =
// tid/COG); NCO consecutive output channels per thread -> one LDS act read +
// one float4/float2 weight load feed NCO FMAs.
template <int WIN, int CIN, int COUT, int NCO, int PXG, int RELU>
__device__ __forceinline__ void layer(const float* __restrict__ sIn, float* __restrict__ sOut,
                                      const float* __restrict__ wp, const float* __restrict__ bias) {
    constexpr int WOUT  = WIN - 2;
    constexpr int NPX   = WOUT * WOUT;
    constexpr int COG   = COUT / NCO;
    constexpr int SLOTS = 512 / COG;
    constexpr int SI    = CIN + 1;
    constexpr int SO    = COUT + 1;

    const int tid = threadIdx.x;
    const int cog = tid % COG;
    const int ps  = tid / COG;
    const int co0 = cog * NCO;

    float acc[PXG][NCO];
    #pragma unroll
    for (int pp = 0; pp < PXG; ++pp)
        #pragma unroll
        for (int c = 0; c < NCO; ++c) acc[pp][c] = bias[co0 + c];

    int basec[PXG];
    #pragma unroll
    for (int pp = 0; pp < PXG; ++pp) {
        int px = ps + pp * SLOTS; if (px >= NPX) px = NPX - 1;   // keep addr valid
        basec[pp] = ((px / WOUT) * WIN + (px % WOUT)) * SI;
    }

    #pragma unroll 2
    for (int ci = 0; ci < CIN; ++ci) {
        #pragma unroll
        for (int k = 0; k < 9; ++k) {
            const int ky = k / 3, kx = k % 3;
            const int off = (ky * WIN + kx) * SI + ci;
            float w[NCO];
            if constexpr (NCO == 4) {
                f4 wv = *(const f4*)(wp + (ci * 9 + k) * COUT + co0);
                w[0] = wv.x; w[1] = wv.y; w[2] = wv.z; w[3] = wv.w;
            } else {
                f2 wv = *(const f2*)(wp + (ci * 9 + k) * COUT + co0);
                w[0] = wv.x; w[1] = wv.y;
            }
            #pragma unroll
            for (int pp = 0; pp < PXG; ++pp) {
                float a = sIn[basec[pp] + off];
                #pragma unroll
                for (int c = 0; c < NCO; ++c)
                    acc[pp][c] = fmaf(w[c], a, acc[pp][c]);
            }
        }
    }

    #pragma unroll
    for (int pp = 0; pp < PXG; ++pp) {
        int px = ps + pp * SLOTS;
        if (px < NPX) {
            #pragma unroll
            for (int c = 0; c < NCO; ++c) {
                float a = acc[pp][c];
                if (RELU) a = fmaxf(a, 0.0f);
                sOut[px * SO + co0 + c] = a;
            }
        }
    }
}

// ---------------------------------------------------------------------------
// Fully fused per-grid-cell pipeline, block = (gx, gy, b), 512 threads.
// 14x14x3 downsampled cone -> conv1..6 (VALID 14->12->10->8->6->4->2) ->
// 2x2 avg pool -> c16[b][gy*16+gx][d][p] (p contiguous).
// Cone coords stay in [1,254]: zero-padding never triggers.
__global__ __launch_bounds__(512)
void fused_cone(const float* __restrict__ x, const float* __restrict__ wp,
                const float* __restrict__ b1, const float* __restrict__ b2,
                const float* __restrict__ b3, const float* __restrict__ b4,
                const float* __restrict__ b5, const float* __restrict__ b6,
                float* __restrict__ c16) {
    __shared__ float sA[3300];   // xin 196*4 / t2 100*33 / t4 36*65 / t6 4*97
    __shared__ float sB[2448];   // t1 144*17 / t3 64*33 / t5 16*65

    const int gx = blockIdx.x, gy = blockIdx.y, b = blockIdx.z;
    const float* xb = x + (size_t)b * 3 * HW1K;

    // xin: xlow cone [14][14][3] (stride 4); xlow[y][x] = avg of x rows
    // 4y+1..4y+2, cols 4x+1..4x+2 (exact bilinear 4x downsample).
    for (int i = threadIdx.x; i < 588; i += 512) {
        int c  = i % 3;
        int t  = i / 3;
        int xi = t % 14;
        int yi = t / 14;
        int ya = 16 * gy + 1 + yi;
        int xa = 16 * gx + 1 + xi;
        const float* p = xb + (size_t)c * HW1K + (4 * ya + 1) * 1024 + (4 * xa + 1);
        sA[(yi * 14 + xi) * 4 + c] = 0.25f * (p[0] + p[1] + p[1024] + p[1025]);
    }
    __syncthreads();

    layer<14,  3, 16, 4, 2, 1>(sA, sB, wp + 0,     b1); __syncthreads();  // 12x12x16
    layer<12, 16, 32, 4, 2, 1>(sB, sA, wp + 432,   b2); __syncthreads();  // 10x10x32
    layer<10, 32, 32, 4, 1, 1>(sA, sB, wp + 5040,  b3); __syncthreads();  // 8x8x32
    layer< 8, 32, 64, 4, 2, 1>(sB, sA, wp + 14256, b4); __syncthreads();  // 6x6x64
    layer< 6, 64, 64, 2, 1, 1>(sA, sB, wp + 32688, b5); __syncthreads();  // 4x4x64
    layer< 4, 64, 96, 2, 1, 0>(sB, sA, wp + 69552, b6); __syncthreads();  // 2x2x96

    // pool 2x2 (exact 16x bilinear downsample); t6 stride 97.
    for (int ch = threadIdx.x; ch < 96; ch += 512) {
        float v = 0.25f * (sA[ch] + sA[97 + ch] + sA[194 + ch] + sA[291 + ch]);
        int p = ch >> 3, d = ch & 7;
        c16[(size_t)b * 24576 + ((gy * 16 + gx) * 8 + d) * 12 + p] = v;
    }
}

// ---------------------------------------------------------------------------
// Fused guide + trilinear slice + affine + clip; 4 px per thread (float4).
// c16 layout: [b][gy*16+gx][d][p=12].
__global__ __launch_bounds__(256)
void slice_apply4(const float* __restrict__ x, const float* __restrict__ c16,
                  float* __restrict__ out) {
    int t = blockIdx.x * 256 + threadIdx.x;      // 0 .. 2*HW1K/4 - 1
    int po4 = t * 4;
    int b   = po4 >> 20;
    int po  = po4 & (HW1K - 1);
    int py  = po >> 10;
    int px0 = po & 1023;

    const float* xb = x + (size_t)b * 3 * HW1K;
    f4 rv  = *(const f4*)(xb + po);
    f4 gv  = *(const f4*)(xb + HW1K + po);
    f4 bv  = *(const f4*)(xb + 2 * HW1K + po);

    float ysf = (float)py * (15.0f / 1023.0f);
    int y0 = (int)floorf(ysf); int y1 = min(y0 + 1, 15);
    float wy = ysf - (float)y0;

    const float* gb = c16 + (size_t)b * 24576;
    f4 outv[3];

    #pragma unroll
    for (int s = 0; s < 4; ++s) {
        float r  = rv[s], g = gv[s], bl = bv[s];
        int   px = px0 + s;

        float gd = fminf(fmaxf(0.299f * r + 0.587f * g + 0.114f * bl, 0.0f), 1.0f);

        float xsf = (float)px * (15.0f / 1023.0f);
        int x0 = (int)floorf(xsf); int x1 = min(x0 + 1, 15);
        float wx = xsf - (float)x0;

        float d  = gd * 7.0f;
        int d0 = (int)floorf(d); d0 = max(0, min(d0, 7));
        int d1 = min(d0 + 1, 7);
        float wd = fminf(fmaxf(d - (float)d0, 0.0f), 1.0f);

        float co[12];
        #pragma unroll
        for (int p = 0; p < 12; ++p) co[p] = 0.0f;

        #pragma unroll
        for (int cy = 0; cy < 2; ++cy) {
            int   yy  = cy ? y1 : y0;
            float wyf = cy ? wy : 1.0f - wy;
            #pragma unroll
            for (int cx = 0; cx < 2; ++cx) {
                int   xx  = cx ? x1 : x0;
                float wyx = wyf * (cx ? wx : 1.0f - wx);
                const float* g0 = gb + ((yy * 16 + xx) * 8 + d0) * 12;
                const float* g1 = gb + ((yy * 16 + xx) * 8 + d1) * 12;
                float wA = wyx * (1.0f - wd), wB = wyx * wd;
                #pragma unroll
                for (int p = 0; p < 12; ++p) co[p] += wA * g0[p] + wB * g1[p];
            }
        }

        #pragma unroll
        for (int i = 0; i < 3; ++i) {
            float v = co[i * 4 + 0] * r + co[i * 4 + 1] * g + co[i * 4 + 2] * bl + co[i * 4 + 3];
            outv[i][s] = fminf(fmaxf(v, 0.0f), 1.0f);
        }
    }

    float* ob = out + (size_t)b * 3 * HW1K;
    #pragma unroll
    for (int i = 0; i < 3; ++i)
        *(f4*)(ob + i * HW1K + po) = outv[i];
}

// ---------------------------------------------------------------------------
extern "C" void kernel_launch(void* const* d_in, const int* in_sizes, int n_in,
                              void* d_out, int out_size, void* d_ws, size_t ws_size,
                              hipStream_t stream) {
    const float* x  = (const float*)d_in[0];
    const float* w1 = (const float*)d_in[1];  const float* b1 = (const float*)d_in[2];
    const float* w2 = (const float*)d_in[3];  const float* b2 = (const float*)d_in[4];
    const float* w3 = (const float*)d_in[5];  const float* b3 = (const float*)d_in[6];
    const float* w4 = (const float*)d_in[7];  const float* b4 = (const float*)d_in[8];
    const float* w5 = (const float*)d_in[9];  const float* b5 = (const float*)d_in[10];
    const float* w6 = (const float*)d_in[11]; const float* b6 = (const float*)d_in[12];
    float* out = (float*)d_out;

    float* wp  = (float*)d_ws;      // 124848 floats
    float* c16 = wp + 124848;       // 2*24576 floats

    prep_w<<<dim3((124848 + 255) / 256), dim3(256), 0, stream>>>(w1, w2, w3, w4, w5, w6, wp);
    fused_cone<<<dim3(16, 16, 2), dim3(512), 0, stream>>>(x, wp, b1, b2, b3, b4, b5, b6, c16);
    slice_apply4<<<dim3(2 * HW1K / 4 / 256), dim3(256), 0, stream>>>(x, c16, out);

    (void)in_sizes; (void)n_in; (void)out_size; (void)ws_size;
}

// Round 5
// 233.486 us; speedup vs baseline: 1.0795x; 1.0795x over previous
//
#include <hip/hip_runtime.h>
#include <hip/hip_bf16.h>

#define HW1K  1048576    // 1024*1024

typedef float f4 __attribute__((ext_vector_type(4)));
typedef float f2 __attribute__((ext_vector_type(2)));

// Weight-prep: OIHW -> wp[layer_base + (ci*9+ky*3+kx)*COUT + co] (co fastest:
// coalesced, f2-aligned over co; all layer bases even).
// Bases: L1@0(432) L2@432(4608) L3@5040(9216) L4@14256(18432) L5@32688(36864)
// L6@69552(55296), total 124848.
__global__ void prep_w(const float* __restrict__ w1, const float* __restrict__ w2,
                       const float* __restrict__ w3, const float* __restrict__ w4,
                       const float* __restrict__ w5, const float* __restrict__ w6,
                       float* __restrict__ wp) {
    int i = blockIdx.x * 256 + threadIdx.x;
    if (i >= 124848) return;
    const float* src; int base, cin, cout;
    if      (i < 432)   { src = w1; base = 0;     cin = 3;  cout = 16; }
    else if (i < 5040)  { src = w2; base = 432;   cin = 16; cout = 32; }
    else if (i < 14256) { src = w3; base = 5040;  cin = 32; cout = 32; }
    else if (i < 32688) { src = w4; base = 14256; cin = 32; cout = 64; }
    else if (i < 69552) { src = w5; base = 32688; cin = 64; cout = 64; }
    else                { src = w6; base = 69552; cin = 64; cout = 96; }
    int r  = i - base;
    int kk = r / cout;
    int co = r % cout;
    int ci = kk / 9;
    int t9 = kk % 9;
    wp[i] = src[(co * cin + ci) * 9 + t9];
}

// ---------------------------------------------------------------------------
// One VALID 3x3 conv layer on LDS tiles, 512 threads. R3-proven structure:
// rolled ci loop (short load bursts), unpadded strides (reads are broadcast /
// <=2-way), coalesced weight loads. NCO in {1,2}: one broadcast LDS act read
// + one f2 weight load feed 2 FMAs.
template <int WIN, int CIN, int COUT, int NCO, int PXG, int RELU>
__device__ __forceinline__ void layer(const float* __restrict__ sIn, float* __restrict__ sOut,
                                      const float* __restrict__ wp, const float* __restrict__ bias) {
    constexpr int WOUT  = WIN - 2;
    constexpr int NPX   = WOUT * WOUT;
    constexpr int COG   = COUT / NCO;
    constexpr int SLOTS = 512 / COG;

    const int tid = threadIdx.x;
    const int cog = tid % COG;
    const int ps  = tid / COG;
    const int co0 = cog * NCO;

    float acc[PXG][NCO];
    #pragma unroll
    for (int pp = 0; pp < PXG; ++pp)
        #pragma unroll
        for (int c = 0; c < NCO; ++c) acc[pp][c] = bias[co0 + c];

    int basec[PXG];
    #pragma unroll
    for (int pp = 0; pp < PXG; ++pp) {
        int px = ps + pp * SLOTS; if (px > NPX - 1) px = NPX - 1;  // keep addr valid
        basec[pp] = ((px / WOUT) * WIN + (px % WOUT)) * CIN;
    }

    for (int ci = 0; ci < CIN; ++ci) {        // rolled: short bursts, good overlap
        #pragma unroll
        for (int k = 0; k < 9; ++k) {
            const int off = ((k / 3) * WIN + (k % 3)) * CIN + ci;
            float w[NCO];
            if constexpr (NCO == 2) {
                f2 wv = *(const f2*)(wp + (ci * 9 + k) * COUT + co0);
                w[0] = wv.x; w[1] = wv.y;
            } else {
                w[0] = wp[(ci * 9 + k) * COUT + co0];
            }
            #pragma unroll
            for (int pp = 0; pp < PXG; ++pp) {
                float a = sIn[basec[pp] + off];
                #pragma unroll
                for (int c = 0; c < NCO; ++c)
                    acc[pp][c] = fmaf(w[c], a, acc[pp][c]);
            }
        }
    }

    #pragma unroll
    for (int pp = 0; pp < PXG; ++pp) {
        int px = ps + pp * SLOTS;
        if (px < NPX) {
            if constexpr (NCO == 2) {
                f2 v;
                v.x = RELU ? fmaxf(acc[pp][0], 0.0f) : acc[pp][0];
                v.y = RELU ? fmaxf(acc[pp][1], 0.0f) : acc[pp][1];
                *(f2*)(sOut + px * COUT + co0) = v;   // even addr: aligned
            } else {
                float a = acc[pp][0];
                if (RELU) a = fmaxf(a, 0.0f);
                sOut[px * COUT + co0] = a;
            }
        }
    }
}

// ---------------------------------------------------------------------------
// Fully fused per-grid-cell pipeline, block = (gx, gy, b), 512 threads.
// 14x14x3 downsampled cone -> conv1..6 (VALID 14->12->10->8->6->4->2) ->
// 2x2 avg pool -> c16[b][gy*16+gx][d][p] (p contiguous).
// Cone coords stay in [1,254]: zero-padding never triggers.
__global__ __launch_bounds__(512)
void fused_cone(const float* __restrict__ x, const float* __restrict__ wp,
                const float* __restrict__ b1, const float* __restrict__ b2,
                const float* __restrict__ b3, const float* __restrict__ b4,
                const float* __restrict__ b5, const float* __restrict__ b6,
                float* __restrict__ c16) {
    __shared__ float sA[3200];   // xin 588 / t2 3200 / t4 2304 / t6 384
    __shared__ float sB[2304];   // t1 2304 / t3 2048 / t5 1024

    const int gx = blockIdx.x, gy = blockIdx.y, b = blockIdx.z;
    const float* xb = x + (size_t)b * 3 * HW1K;

    // xin: xlow cone [14][14][3]; xlow[y][x] = avg of x rows 4y+1..4y+2,
    // cols 4x+1..4x+2 (exact bilinear 4x downsample).
    for (int i = threadIdx.x; i < 588; i += 512) {
        int c  = i % 3;
        int t  = i / 3;
        int xi = t % 14;
        int yi = t / 14;
        int ya = 16 * gy + 1 + yi;
        int xa = 16 * gx + 1 + xi;
        const float* p = xb + (size_t)c * HW1K + (4 * ya + 1) * 1024 + (4 * xa + 1);
        sA[(yi * 14 + xi) * 3 + c] = 0.25f * (p[0] + p[1] + p[1024] + p[1025]);
    }
    __syncthreads();

    // (WIN, CIN, COUT, NCO, PXG): COG=COUT/NCO, SLOTS=512/COG covers NPX.
    layer<14,  3, 16, 2, 3, 1>(sA, sB, wp + 0,     b1); __syncthreads();  // 12x12x16
    layer<12, 16, 32, 2, 4, 1>(sB, sA, wp + 432,   b2); __syncthreads();  // 10x10x32
    layer<10, 32, 32, 1, 4, 1>(sA, sB, wp + 5040,  b3); __syncthreads();  // 8x8x32 (NCO=1: keeps stride-32 reads 2-way)
    layer< 8, 32, 64, 2, 3, 1>(sB, sA, wp + 14256, b4); __syncthreads();  // 6x6x64
    layer< 6, 64, 64, 2, 1, 1>(sA, sB, wp + 32688, b5); __syncthreads();  // 4x4x64
    layer< 4, 64, 96, 2, 1, 0>(sB, sA, wp + 69552, b6); __syncthreads();  // 2x2x96

    // pool 2x2 (exact 16x bilinear downsample); t6 stride 96.
    for (int ch = threadIdx.x; ch < 96; ch += 512) {
        float v = 0.25f * (sA[ch] + sA[96 + ch] + sA[192 + ch] + sA[288 + ch]);
        int p = ch >> 3, d = ch & 7;
        c16[(size_t)b * 24576 + ((gy * 16 + gx) * 8 + d) * 12 + p] = v;
    }
}

// ---------------------------------------------------------------------------
// Fused guide + trilinear slice + affine + clip; 4 px per thread (float4).
// c16 layout: [b][gy*16+gx][d][p=12].
__global__ __launch_bounds__(256)
void slice_apply4(const float* __restrict__ x, const float* __restrict__ c16,
                  float* __restrict__ out) {
    int t = blockIdx.x * 256 + threadIdx.x;      // 0 .. 2*HW1K/4 - 1
    int po4 = t * 4;
    int b   = po4 >> 20;
    int po  = po4 & (HW1K - 1);
    int py  = po >> 10;
    int px0 = po & 1023;

    const float* xb = x + (size_t)b * 3 * HW1K;
    f4 rv  = *(const f4*)(xb + po);
    f4 gv  = *(const f4*)(xb + HW1K + po);
    f4 bv  = *(const f4*)(xb + 2 * HW1K + po);

    float ysf = (float)py * (15.0f / 1023.0f);
    int y0 = (int)floorf(ysf); int y1 = min(y0 + 1, 15);
    float wy = ysf - (float)y0;

    const float* gb = c16 + (size_t)b * 24576;
    f4 outv[3];

    #pragma unroll
    for (int s = 0; s < 4; ++s) {
        float r  = rv[s], g = gv[s], bl = bv[s];
        int   px = px0 + s;

        float gd = fminf(fmaxf(0.299f * r + 0.587f * g + 0.114f * bl, 0.0f), 1.0f);

        float xsf = (float)px * (15.0f / 1023.0f);
        int x0 = (int)floorf(xsf); int x1 = min(x0 + 1, 15);
        float wx = xsf - (float)x0;

        float d  = gd * 7.0f;
        int d0 = (int)floorf(d); d0 = max(0, min(d0, 7));
        int d1 = min(d0 + 1, 7);
        float wd = fminf(fmaxf(d - (float)d0, 0.0f), 1.0f);

        float co[12];
        #pragma unroll
        for (int p = 0; p < 12; ++p) co[p] = 0.0f;

        #pragma unroll
        for (int cy = 0; cy < 2; ++cy) {
            int   yy  = cy ? y1 : y0;
            float wyf = cy ? wy : 1.0f - wy;
            #pragma unroll
            for (int cx = 0; cx < 2; ++cx) {
                int   xx  = cx ? x1 : x0;
                float wyx = wyf * (cx ? wx : 1.0f - wx);
                const float* g0 = gb + ((yy * 16 + xx) * 8 + d0) * 12;
                const float* g1 = gb + ((yy * 16 + xx) * 8 + d1) * 12;
                float wA = wyx * (1.0f - wd), wB = wyx * wd;
                #pragma unroll
                for (int p = 0; p < 12; ++p) co[p] += wA * g0[p] + wB * g1[p];
            }
        }

        #pragma unroll
        for (int i = 0; i < 3; ++i) {
            float v = co[i * 4 + 0] * r + co[i * 4 + 1] * g + co[i * 4 + 2] * bl + co[i * 4 + 3];
            outv[i][s] = fminf(fmaxf(v, 0.0f), 1.0f);
        }
    }

    float* ob = out + (size_t)b * 3 * HW1K;
    #pragma unroll
    for (int i = 0; i < 3; ++i)
        *(f4*)(ob + i * HW1K + po) = outv[i];
}

// ---------------------------------------------------------------------------
extern "C" void kernel_launch(void* const* d_in, const int* in_sizes, int n_in,
                              void* d_out, int out_size, void* d_ws, size_t ws_size,
                              hipStream_t stream) {
    const float* x  = (const float*)d_in[0];
    const float* w1 = (const float*)d_in[1];  const float* b1 = (const float*)d_in[2];
    const float* w2 = (const float*)d_in[3];  const float* b2 = (const float*)d_in[4];
    const float* w3 = (const float*)d_in[5];  const float* b3 = (const float*)d_in[6];
    const float* w4 = (const float*)d_in[7];  const float* b4 = (const float*)d_in[8];
    const float* w5 = (const float*)d_in[9];  const float* b5 = (const float*)d_in[10];
    const float* w6 = (const float*)d_in[11]; const float* b6 = (const float*)d_in[12];
    float* out = (float*)d_out;

    float* wp  = (float*)d_ws;      // 124848 floats
    float* c16 = wp + 124848;       // 2*24576 floats

    prep_w<<<dim3((124848 + 255) / 256), dim3(256), 0, stream>>>(w1, w2, w3, w4, w5, w6, wp);
    fused_cone<<<dim3(16, 16, 2), dim3(512), 0, stream>>>(x, wp, b1, b2, b3, b4, b5, b6, c16);
    slice_apply4<<<dim3(2 * HW1K / 4 / 256), dim3(256), 0, stream>>>(x, c16, out);

    (void)in_sizes; (void)n_in; (void)out_size; (void)ws_size;
}

// Round 6
// 132.491 us; speedup vs baseline: 1.9024x; 1.7623x over previous
//
#include <hip/hip_runtime.h>
#include <hip/hip_bf16.h>

#define HW1K  1048576    // 1024*1024

typedef float f4 __attribute__((ext_vector_type(4)));

__device__ __forceinline__ f4 relu4(f4 v) {
    v.x = fmaxf(v.x, 0.0f); v.y = fmaxf(v.y, 0.0f);
    v.z = fmaxf(v.z, 0.0f); v.w = fmaxf(v.w, 0.0f);
    return v;
}

// Weight-prep: OIHW -> wp[layer_base + (ci*9+ky*3+kx)*COUT + co] (co fastest:
// coalesced, f4-aligned over co; all layer bases mult of 4).
// Bases: L1@0(432) L2@432(4608) L3@5040(9216) L4@14256(18432) L5@32688(36864)
// L6@69552(55296), total 124848.
__global__ void prep_w(const float* __restrict__ w1, const float* __restrict__ w2,
                       const float* __restrict__ w3, const float* __restrict__ w4,
                       const float* __restrict__ w5, const float* __restrict__ w6,
                       float* __restrict__ wp) {
    int i = blockIdx.x * 256 + threadIdx.x;
    if (i >= 124848) return;
    const float* src; int base, cin, cout;
    if      (i < 432)   { src = w1; base = 0;     cin = 3;  cout = 16; }
    else if (i < 5040)  { src = w2; base = 432;   cin = 16; cout = 32; }
    else if (i < 14256) { src = w3; base = 5040;  cin = 32; cout = 32; }
    else if (i < 32688) { src = w4; base = 14256; cin = 32; cout = 64; }
    else if (i < 69552) { src = w5; base = 32688; cin = 64; cout = 64; }
    else                { src = w6; base = 69552; cin = 64; cout = 96; }
    int r  = i - base;
    int kk = r / cout;
    int co = r % cout;
    int ci = kk / 9;
    int t9 = kk % 9;
    wp[i] = src[(co * cin + ci) * 9 + t9];
}

// ---------------------------------------------------------------------------
// Strip conv layer on LDS (256 threads): thread = (cog = tid%COG -> 4 output
// channels, strip-slot ps = tid/COG -> 1x2 px strip). ci blocked by 4:
// act window = 3x4 f4 (ds_read_b128), weights f4 over co -> per ci4:
// 12 ds_b128 + 36 f4 vmem feed 288 FMAs (ds/FMA=1/24, vmem/FMA=1/8).
// Strides SI=CIN+4, SO=COUT+4 (16B-aligned, distinct bank-quads).
template <int WIN, int CIN, int COUT, int SPT, int RELU>
__device__ __forceinline__ void layer_s(const float* __restrict__ sIn, float* __restrict__ sOut,
                                        const float* __restrict__ wp, const float* __restrict__ bias) {
    constexpr int WOUT = WIN - 2;
    constexpr int SI   = CIN + 4;
    constexpr int SO   = COUT + 4;
    constexpr int COG  = COUT / 4;
    constexpr int SLOTS = 256 / COG;
    constexpr int HSTR = WOUT / 2;
    constexpr int NSTR = WOUT * HSTR;

    const int tid = threadIdx.x;
    const int cog = tid % COG;
    const int co0 = cog * 4;
    const int ps  = tid / COG;

    const f4 bs = *(const f4*)(bias + co0);

    #pragma unroll
    for (int s = 0; s < SPT; ++s) {
        int ss = ps + s * SLOTS;
        if (ss > NSTR - 1) ss = NSTR - 1;          // duplicates write same value
        const int row  = ss / HSTR;
        const int col2 = (ss % HSTR) * 2;
        const int base = (row * WIN + col2) * SI;

        f4 acc0 = bs, acc1 = bs;

        for (int ci4 = 0; ci4 < CIN / 4; ++ci4) {
            f4 a[3][4];
            #pragma unroll
            for (int r = 0; r < 3; ++r)
                #pragma unroll
                for (int c = 0; c < 4; ++c)
                    a[r][c] = *(const f4*)(sIn + base + (r * WIN + c) * SI + ci4 * 4);
            #pragma unroll
            for (int cc = 0; cc < 4; ++cc) {
                #pragma unroll
                for (int ky = 0; ky < 3; ++ky) {
                    #pragma unroll
                    for (int kx = 0; kx < 3; ++kx) {
                        f4 w = *(const f4*)(wp + ((ci4 * 4 + cc) * 9 + ky * 3 + kx) * COUT + co0);
                        acc0 += w * a[ky][kx][cc];
                        acc1 += w * a[ky][kx + 1][cc];
                    }
                }
            }
        }
        if (RELU) { acc0 = relu4(acc0); acc1 = relu4(acc1); }
        const int opx = row * WOUT + col2;
        *(f4*)(sOut + opx * SO + co0)       = acc0;
        *(f4*)(sOut + (opx + 1) * SO + co0) = acc1;
    }
}

// Single-px-per-thread variant (L5: 16 px x 16 cog = 256 threads exactly).
template <int WIN, int CIN, int COUT, int RELU>
__device__ __forceinline__ void layer_p(const float* __restrict__ sIn, float* __restrict__ sOut,
                                        const float* __restrict__ wp, const float* __restrict__ bias) {
    constexpr int WOUT = WIN - 2;
    constexpr int SI   = CIN + 4;
    constexpr int SO   = COUT + 4;
    constexpr int COG  = COUT / 4;

    const int tid = threadIdx.x;
    const int cog = tid % COG;
    const int co0 = cog * 4;
    const int px  = tid / COG;          // 0..NPX-1 (exact)
    const int row = px / WOUT, col = px % WOUT;
    const int base = (row * WIN + col) * SI;

    f4 acc = *(const f4*)(bias + co0);

    for (int ci4 = 0; ci4 < CIN / 4; ++ci4) {
        f4 a[3][3];
        #pragma unroll
        for (int r = 0; r < 3; ++r)
            #pragma unroll
            for (int c = 0; c < 3; ++c)
                a[r][c] = *(const f4*)(sIn + base + (r * WIN + c) * SI + ci4 * 4);
        #pragma unroll
        for (int cc = 0; cc < 4; ++cc)
            #pragma unroll
            for (int k = 0; k < 9; ++k) {
                f4 w = *(const f4*)(wp + ((ci4 * 4 + cc) * 9 + k) * COUT + co0);
                acc += w * a[k / 3][k % 3][cc];
            }
    }
    if (RELU) acc = relu4(acc);
    *(f4*)(sOut + px * SO + co0) = acc;
}

// ---------------------------------------------------------------------------
// Fully fused per-grid-cell pipeline, block = (gx, gy, b), 256 threads.
// 14x14x3 cone -> conv1..6 (VALID 14->12->10->8->6->4->2) -> 2x2 pool ->
// c16[b][gy*16+gx][d][p]. Cone coords in [1,254]: padding never triggers.
__global__ __launch_bounds__(256)
void fused_cone(const float* __restrict__ x, const float* __restrict__ wp,
                const float* __restrict__ b1, const float* __restrict__ b2,
                const float* __restrict__ b3, const float* __restrict__ b4,
                const float* __restrict__ b5, const float* __restrict__ b6,
                float* __restrict__ c16) {
    __shared__ float sA[3600];   // xin 196*4=784 / t2 100*36=3600 / t4 36*68=2448 / L6 scratch 768
    __shared__ float sB[2880];   // t1 144*20=2880 / t3 64*36=2304 / t5 16*68=1088

    const int gx = blockIdx.x, gy = blockIdx.y, b = blockIdx.z;
    const float* xb = x + (size_t)b * 3 * HW1K;

    // xin: xlow cone [14*14][4-stride]; xlow[y][x] = avg of x rows 4y+1..4y+2,
    // cols 4x+1..4x+2 (exact bilinear 4x downsample).
    for (int i = threadIdx.x; i < 588; i += 256) {
        int c  = i % 3;
        int t  = i / 3;
        int xi = t % 14;
        int yi = t / 14;
        int ya = 16 * gy + 1 + yi;
        int xa = 16 * gx + 1 + xi;
        const float* p = xb + (size_t)c * HW1K + (4 * ya + 1) * 1024 + (4 * xa + 1);
        sA[t * 4 + c] = 0.25f * (p[0] + p[1] + p[1024] + p[1025]);
    }
    __syncthreads();

    // L1: CIN=3 special (scalar act reads), 3 px per thread. out t1 [144][20].
    {
        const int cog = threadIdx.x % 4, co0 = cog * 4, ps = threadIdx.x / 4;
        const f4 bs = *(const f4*)(b1 + co0);
        f4 acc[3]; int base[3], pxc[3];
        #pragma unroll
        for (int pp = 0; pp < 3; ++pp) {
            int px = ps + pp * 64; if (px > 143) px = 143;
            pxc[pp]  = px;
            base[pp] = ((px / 12) * 14 + (px % 12)) * 4;
            acc[pp]  = bs;
        }
        for (int ci = 0; ci < 3; ++ci) {
            #pragma unroll
            for (int k = 0; k < 9; ++k) {
                f4 w = *(const f4*)(wp + (ci * 9 + k) * 16 + co0);
                int off = ((k / 3) * 14 + (k % 3)) * 4 + ci;
                #pragma unroll
                for (int pp = 0; pp < 3; ++pp)
                    acc[pp] += w * sA[base[pp] + off];
            }
        }
        #pragma unroll
        for (int pp = 0; pp < 3; ++pp)
            *(f4*)(sB + pxc[pp] * 20 + co0) = relu4(acc[pp]);
    }
    __syncthreads();

    layer_s<12, 16, 32, 2, 1>(sB, sA, wp + 432,   b2); __syncthreads();  // t2 [100][36]
    layer_s<10, 32, 32, 1, 1>(sA, sB, wp + 5040,  b3); __syncthreads();  // t3 [64][36]
    layer_s< 8, 32, 64, 2, 1>(sB, sA, wp + 14256, b4); __syncthreads();  // t4 [36][68]
    layer_p< 6, 64, 64, 1>   (sA, sB, wp + 32688, b5); __syncthreads();  // t5 [16][68]

    // L6: CIN=64, COUT=96, WIN=4->WOUT=2 (4 px), ci split in 2 halves of 32.
    // Active: 2*96 threads; partials to sA scratch [half][4][96]; no ReLU.
    {
        const int r    = threadIdx.x & 127;
        const int half = threadIdx.x >> 7;
        if (r < 96) {
            const int cog = r % 24, co0 = cog * 4, px = r / 24;
            const int base = ((px >> 1) * 4 + (px & 1)) * 68;
            f4 acc;
            if (half == 0) acc = *(const f4*)(b6 + co0);
            else           acc = f4{0.0f, 0.0f, 0.0f, 0.0f};
            for (int ci4 = half * 8; ci4 < half * 8 + 8; ++ci4) {
                f4 a[3][3];
                #pragma unroll
                for (int rr = 0; rr < 3; ++rr)
                    #pragma unroll
                    for (int c = 0; c < 3; ++c)
                        a[rr][c] = *(const f4*)(sB + base + (rr * 4 + c) * 68 + ci4 * 4);
                #pragma unroll
                for (int cc = 0; cc < 4; ++cc)
                    #pragma unroll
                    for (int k = 0; k < 9; ++k) {
                        f4 w = *(const f4*)(wp + 69552 + ((ci4 * 4 + cc) * 9 + k) * 96 + co0);
                        acc += w * a[k / 3][k % 3][cc];
                    }
            }
            *(f4*)(sA + half * 384 + px * 96 + co0) = acc;
        }
    }
    __syncthreads();

    // pool 2x2 (exact 16x bilinear downsample) + combine ci halves.
    if (threadIdx.x < 96) {
        const int ch = threadIdx.x;
        float v = 0.0f;
        #pragma unroll
        for (int px = 0; px < 4; ++px)
            v += sA[px * 96 + ch] + sA[384 + px * 96 + ch];
        v *= 0.25f;
        int p = ch >> 3, d = ch & 7;
        c16[(size_t)b * 24576 + ((gy * 16 + gx) * 8 + d) * 12 + p] = v;
    }
}

// ---------------------------------------------------------------------------
// Fused guide + trilinear slice + affine + clip; 4 px per thread (float4).
// c16 layout: [b][gy*16+gx][d][p=12].
__global__ __launch_bounds__(256)
void slice_apply4(const float* __restrict__ x, const float* __restrict__ c16,
                  float* __restrict__ out) {
    int t = blockIdx.x * 256 + threadIdx.x;      // 0 .. 2*HW1K/4 - 1
    int po4 = t * 4;
    int b   = po4 >> 20;
    int po  = po4 & (HW1K - 1);
    int py  = po >> 10;
    int px0 = po & 1023;

    const float* xb = x + (size_t)b * 3 * HW1K;
    f4 rv  = *(const f4*)(xb + po);
    f4 gv  = *(const f4*)(xb + HW1K + po);
    f4 bv  = *(const f4*)(xb + 2 * HW1K + po);

    float ysf = (float)py * (15.0f / 1023.0f);
    int y0 = (int)floorf(ysf); int y1 = min(y0 + 1, 15);
    float wy = ysf - (float)y0;

    const float* gb = c16 + (size_t)b * 24576;
    f4 outv[3];

    #pragma unroll
    for (int s = 0; s < 4; ++s) {
        float r  = rv[s], g = gv[s], bl = bv[s];
        int   px = px0 + s;

        float gd = fminf(fmaxf(0.299f * r + 0.587f * g + 0.114f * bl, 0.0f), 1.0f);

        float xsf = (float)px * (15.0f / 1023.0f);
        int x0 = (int)floorf(xsf); int x1 = min(x0 + 1, 15);
        float wx = xsf - (float)x0;

        float d  = gd * 7.0f;
        int d0 = (int)floorf(d); d0 = max(0, min(d0, 7));
        int d1 = min(d0 + 1, 7);
        float wd = fminf(fmaxf(d - (float)d0, 0.0f), 1.0f);

        float co[12];
        #pragma unroll
        for (int p = 0; p < 12; ++p) co[p] = 0.0f;

        #pragma unroll
        for (int cy = 0; cy < 2; ++cy) {
            int   yy  = cy ? y1 : y0;
            float wyf = cy ? wy : 1.0f - wy;
            #pragma unroll
            for (int cx = 0; cx < 2; ++cx) {
                int   xx  = cx ? x1 : x0;
                float wyx = wyf * (cx ? wx : 1.0f - wx);
                const float* g0 = gb + ((yy * 16 + xx) * 8 + d0) * 12;
                const float* g1 = gb + ((yy * 16 + xx) * 8 + d1) * 12;
                float wA = wyx * (1.0f - wd), wB = wyx * wd;
                #pragma unroll
                for (int p = 0; p < 12; ++p) co[p] += wA * g0[p] + wB * g1[p];
            }
        }

        #pragma unroll
        for (int i = 0; i < 3; ++i) {
            float v = co[i * 4 + 0] * r + co[i * 4 + 1] * g + co[i * 4 + 2] * bl + co[i * 4 + 3];
            outv[i][s] = fminf(fmaxf(v, 0.0f), 1.0f);
        }
    }

    float* ob = out + (size_t)b * 3 * HW1K;
    #pragma unroll
    for (int i = 0; i < 3; ++i)
        *(f4*)(ob + i * HW1K + po) = outv[i];
}

// ---------------------------------------------------------------------------
extern "C" void kernel_launch(void* const* d_in, const int* in_sizes, int n_in,
                              void* d_out, int out_size, void* d_ws, size_t ws_size,
                              hipStream_t stream) {
    const float* x  = (const float*)d_in[0];
    const float* w1 = (const float*)d_in[1];  const float* b1 = (const float*)d_in[2];
    const float* w2 = (const float*)d_in[3];  const float* b2 = (const float*)d_in[4];
    const float* w3 = (const float*)d_in[5];  const float* b3 = (const float*)d_in[6];
    const float* w4 = (const float*)d_in[7];  const float* b4 = (const float*)d_in[8];
    const float* w5 = (const float*)d_in[9];  const float* b5 = (const float*)d_in[10];
    const float* w6 = (const float*)d_in[11]; const float* b6 = (const float*)d_in[12];
    float* out = (float*)d_out;

    float* wp  = (float*)d_ws;      // 124848 floats
    float* c16 = wp + 124848;       // 2*24576 floats

    prep_w<<<dim3((124848 + 255) / 256), dim3(256), 0, stream>>>(w1, w2, w3, w4, w5, w6, wp);
    fused_cone<<<dim3(16, 16, 2), dim3(256), 0, stream>>>(x, wp, b1, b2, b3, b4, b5, b6, c16);
    slice_apply4<<<dim3(2 * HW1K / 4 / 256), dim3(256), 0, stream>>>(x, c16, out);

    (void)in_sizes; (void)n_in; (void)out_size; (void)ws_size;
}